// Round 5
// baseline (317.496 us; speedup 1.0000x reference)
//
#include <hip/hip_runtime.h>

// BmmEnsemble: species-routed 4x8 MLP ensemble (384->160->128->96->1, CELU 0.1),
// mean over 8 models, global sum -> scalar.
// R10: OCCUPANCY 2->3. R6(regs-shape)/R9(unpinned sched) neutral, R7/R8
// regressed => every 2-waves/SIMD variant lands ~225us with all pipes <25%
// busy: latency-bound at 2 waves/SIMD. Three caps held occupancy at 2:
// LDS 63.5KB (>53.3 => 2 blocks/CU), unified regs ~200 (120 arch + 80 acc
// > 170 => 2 waves/SIMD), launch_bounds(,2) licensing 256 regs. This round:
// (1) LDS 51.2KB: hpar dropped (biases from global in epilogues -- legal now
// that no vmcnt asm exists), 4KB chunks x2 buffers; (2) accumulator N-split:
// each layer computed in two N-halves so peak live acc = C[2][5]=40 regs
// (stream re-packed in pass order); (3) __launch_bounds__(256,3).
// 784 blocks = 3.06/CU -> one 3-block generation, 12 waves/CU.

#define NSP 4
#define NMODELS 8
#define MSPLIT 2
#define MPB (NMODELS / MSPLIT)       // 4 models per block
#define NATOMS 50000
#define NPER (NATOMS / NSP)          // 12500
#define D0 384
#define D1 160
#define D2 128
#define D3 96
#define NRBLK ((NATOMS + 255) / 256) // 196
#define ABLK 128
#define BPS ((NPER + ABLK - 1) / ABLK) // 98 blocks per species
#define FRAGS_SM 184                  // 120 (W1) + 40 (W2) + 24 (W3) fragments
#define CHUNKS_M 46                   // 184 frags / 4 per chunk
#define TOT_CHUNKS (MPB * CHUNKS_M)   // 184 chunks per block

typedef float f32x4 __attribute__((ext_vector_type(4)));
typedef __bf16 bf16x8 __attribute__((ext_vector_type(8)));

#define MFMA16(a, b, c) __builtin_amdgcn_mfma_f32_16x16x32_bf16((a), (b), (c), 0, 0, 0)

// ---- workspace layout (bytes) ----
#define PALL_BYTES ((size_t)NSP * NMODELS * FRAGS_SM * 1024)
#define PBIAS_OFF PALL_BYTES
#define PBIAS_BYTES ((size_t)NSP * NMODELS * 512 * 2)   // 1KB per (s,m)
#define ORDER_OFF (PBIAS_OFF + PBIAS_BYTES)
#define BCNT_OFF (ORDER_OFF + (size_t)NATOMS * 4)
#define BPFX_OFF (BCNT_OFF + (size_t)NRBLK * NSP * 4)
#define BASE_OFF (BPFX_OFF + (size_t)NRBLK * NSP * 4)

static __device__ __forceinline__ unsigned short bfbits(float f) {
  __bf16 h = (__bf16)f;
  return __builtin_bit_cast(unsigned short, h);
}

static __device__ __forceinline__ float celu01(float x) {
  // celu(x, alpha=0.1) = max(x,0) + min(0, 0.1*(exp(x/0.1)-1))
  return fmaxf(x, 0.f) + 0.1f * fminf(0.f, __expf(x * 10.f) - 1.f);
}

// async global->LDS, 16 B per lane; LDS dest = wave-uniform base + lane*16
static __device__ __forceinline__ void gload16(const void* g, void* l) {
  __builtin_amdgcn_global_load_lds(
      (const __attribute__((address_space(1))) unsigned int*)g,
      (__attribute__((address_space(3))) unsigned int*)l, 16, 0, 0);
}

// ---------------- routing ----------------
__global__ __launch_bounds__(256) void count_kernel(const int* __restrict__ species,
                                                    int* __restrict__ bcnt) {
  __shared__ int cnt[NSP];
  int t = threadIdx.x;
  if (t < NSP) cnt[t] = 0;
  __syncthreads();
  int i = blockIdx.x * 256 + t;
  if (i < NATOMS) atomicAdd(&cnt[species[i]], 1);
  __syncthreads();
  if (t < NSP) bcnt[blockIdx.x * NSP + t] = cnt[t];
}

__global__ __launch_bounds__(256) void scan_kernel(const int* __restrict__ bcnt,
                                                   int* __restrict__ bpfx,
                                                   int* __restrict__ base) {
  int w = threadIdx.x >> 6;
  int lane = threadIdx.x & 63;
  __shared__ int totals[NSP];
  int carry = 0;
  for (int c = 0; c < (NRBLK + 63) / 64; ++c) {
    int idx = c * 64 + lane;
    int v = (idx < NRBLK) ? bcnt[idx * NSP + w] : 0;
    int incl = v;
    for (int off = 1; off < 64; off <<= 1) {
      int tv = __shfl_up(incl, off);
      if (lane >= off) incl += tv;
    }
    if (idx < NRBLK) bpfx[idx * NSP + w] = carry + incl - v;
    carry += __shfl(incl, 63);
  }
  if (lane == 0) totals[w] = carry;
  __syncthreads();
  if (threadIdx.x == 0) {
    int run = 0;
    for (int s = 0; s < NSP; ++s) { base[s] = run; run += totals[s]; }
  }
}

__global__ __launch_bounds__(256) void route_kernel(const int* __restrict__ species,
                                                    const int* __restrict__ bpfx,
                                                    const int* __restrict__ base,
                                                    int* __restrict__ order) {
  __shared__ int sp[256];
  int t = threadIdx.x;
  int i = blockIdx.x * 256 + t;
  sp[t] = (i < NATOMS) ? species[i] : -1;
  __syncthreads();
  if (i < NATOMS) {
    int s = sp[t];
    int rank = 0;
    for (int j = 0; j < t; ++j) rank += (sp[j] == s) ? 1 : 0;
    order[base[s] + bpfx[blockIdx.x * NSP + s] + rank] = i;
  }
}

// ---------------- weight pre-pack into contiguous B-fragment stream ----------------
// pAll: per (s,m) block of FRAGS_SM fragments (1 KB each), ordered in PASSES:
// within a pass, f = kf*NT + nth; col n = colBase + nth*16 + (l&15);
// k = kf*32 + 8*(l>>4) + e. Lane l, dword d packs elems k=...+2d, 2d+1.
__global__ __launch_bounds__(256) void pack_kernel(const float* __restrict__ W,
                                                   unsigned* __restrict__ dst,
                                                   int K, int Nstride, int NT,
                                                   int colBase, int fragBase,
                                                   int total) {
  int tid = blockIdx.x * 256 + threadIdx.x;
  if (tid >= total) return;
  int per_sm = K * NT * 8;           // dwords per (s,m) for this pass
  int smi = tid / per_sm;
  int rem = tid - smi * per_sm;
  int frag = rem >> 8;               // 256 dwords per fragment
  int wi = rem & 255;
  int l = wi >> 2, d = wi & 3;
  int kf = frag / NT;
  int nt = frag - kf * NT;
  int k = kf * 32 + ((l >> 4) << 3) + 2 * d;
  int n = colBase + nt * 16 + (l & 15);
  const float* p = W + ((size_t)smi * K + k) * Nstride + n;
  unsigned lo = bfbits(p[0]);
  unsigned hi = bfbits(p[Nstride]);
  dst[((size_t)smi * FRAGS_SM + fragBase + frag) * 256 + wi] = lo | (hi << 16);
}

// param pack: per (s,m) record of 512 shorts:
// [0:160) b1 bf16 | [160:288) b2 bf16 | [288:384) b3 bf16 | [384:480) W4 bf16 |
// [480:482) b4 as f32 bit halves | rest 0
__global__ __launch_bounds__(256) void param_pack(const float* __restrict__ b1,
                                                  const float* __restrict__ b2,
                                                  const float* __restrict__ b3,
                                                  const float* __restrict__ W4,
                                                  const float* __restrict__ b4,
                                                  unsigned short* __restrict__ dst) {
  int i = blockIdx.x * 256 + threadIdx.x;
  if (i >= NSP * NMODELS * 512) return;
  int smi = i >> 9, o = i & 511;
  unsigned short v = 0;
  if (o < 160) v = bfbits(b1[smi * 160 + o]);
  else if (o < 288) v = bfbits(b2[smi * 128 + (o - 160)]);
  else if (o < 384) v = bfbits(b3[smi * 96 + (o - 288)]);
  else if (o < 480) v = bfbits(W4[smi * 96 + (o - 384)]);
  else if (o < 482) {
    unsigned u = __builtin_bit_cast(unsigned, b4[smi]);
    v = (unsigned short)((o == 480) ? (u & 0xffffu) : (u >> 16));
  }
  dst[i] = v;
}

// ---------------- fused MLP (3 blocks/CU, N-split accumulators) ----------------
__global__ __launch_bounds__(256, 3) void mlp_kernel(
    const float* __restrict__ aev, const int* __restrict__ order,
    const unsigned short* __restrict__ pAll, const unsigned short* __restrict__ pPar,
    float* __restrict__ out) {
  __shared__ alignas(16) unsigned short stage[2][2048]; // 8192 B, 2 x 4KB chunks
  __shared__ alignas(16) __bf16 hbuf[4][32][168];       // 43008 B, padded rows
  // total LDS = 51200 B -> 3 blocks/CU

  // XCD-aware swizzle (784 % 8 == 0): each XCD gets 98 consecutive blocks,
  // all sharing one (species, model-half) weight stream (736 KB) in its L2.
  const int nwg = NSP * BPS * MSPLIT;
  const int cpx = nwg / 8;
  const int blk = (blockIdx.x % 8) * cpx + blockIdx.x / 8;
  const int s = blk / (BPS * MSPLIT);
  const int rem = blk - s * (BPS * MSPLIT);
  const int mh = rem / BPS;          // model half: models mh*4 .. mh*4+3
  const int sb = rem - mh * BPS;     // atom block within species
  const int tid = threadIdx.x;
  const int w = tid >> 6;
  const int l = tid & 63;
  const int l15 = l & 15;
  const int l4 = l >> 4;

  // per-wave weight-stream source: each wave owns 1KB (=1 frag) of each 4KB chunk
  const size_t smBase = (size_t)(s * NMODELS + mh * MPB) * FRAGS_SM;
  const char* wsrc = (const char*)pAll + smBase * 1024 + (size_t)w * 1024 + (size_t)l * 16;

  // per-block param record base (biases read from global; L2-hot)
  const unsigned short* parBf = pPar + (size_t)(s * NMODELS + mh * MPB) * 512;
  auto ldbf = [&](int off) -> float {
    return (float)__builtin_bit_cast(__bf16, parBf[off]);
  };

  // ---- A1 fragments: 2 M-tiles x 12 K-frags per wave, resident across models ----
  bf16x8 a1[2][12];
#pragma unroll
  for (int mt = 0; mt < 2; ++mt) {
    int slot = sb * ABLK + w * 32 + mt * 16 + l15;
    int g = (slot < NPER) ? order[s * NPER + slot] : -1;
    if (g >= 0) {
      const float* rp = aev + (size_t)g * D0 + l4 * 8;
#pragma unroll
      for (int kf = 0; kf < 12; ++kf) {
        const float4* q = (const float4*)(rp + kf * 32);
        float4 lo = q[0], hi = q[1];
        bf16x8 f;
        f[0] = (__bf16)lo.x; f[1] = (__bf16)lo.y; f[2] = (__bf16)lo.z; f[3] = (__bf16)lo.w;
        f[4] = (__bf16)hi.x; f[5] = (__bf16)hi.y; f[6] = (__bf16)hi.z; f[7] = (__bf16)hi.w;
        a1[mt][kf] = f;
      }
    } else {
#pragma unroll
      for (int kf = 0; kf < 12; ++kf) {
        bf16x8 z;
#pragma unroll
        for (int e = 0; e < 8; ++e) z[e] = (__bf16)0.f;
        a1[mt][kf] = z;
      }
    }
  }

  float acc4[2][4] = {{0.f, 0.f, 0.f, 0.f}, {0.f, 0.f, 0.f, 0.f}};
  float bbacc = 0.f;

  // ---- stage chunk 0; first __syncthreads drains it ----
  gload16(wsrc, (char*)stage + w * 1024);
  __syncthreads();

  auto stage_next = [&](int gn) {
    if (gn < TOT_CHUNKS)
      gload16(wsrc + (size_t)gn * 4096,
              (char*)stage + ((gn & 1) << 12) + w * 1024);
  };

  int gc = 0; // global chunk index being computed

  // Model loop rolled; gc loop-carried. Per model: 46 chunks in 6 passes.
#pragma unroll 1
  for (int m = 0; m < MPB; ++m) {
    // ===== Layer 1: [32,384]x[384,160] in two N-halves of 80 (15 chunks ea) =====
#pragma unroll 1
    for (int p = 0; p < 2; ++p) {
      f32x4 C[2][5];
#pragma unroll
      for (int mt = 0; mt < 2; ++mt)
#pragma unroll
        for (int nt = 0; nt < 5; ++nt) {
          f32x4 z; z[0] = z[1] = z[2] = z[3] = 0.f; C[mt][nt] = z;
        }
#pragma unroll
      for (int c = 0; c < 15; ++c) {
        stage_next(gc + 1);
        const bf16x8* sbuf = (const bf16x8*)((const char*)stage + ((gc & 1) << 12));
#pragma unroll
        for (int j = 0; j < 4; ++j) {
          const int f = c * 4 + j;    // kf = f/5, nth = f%5 (compile-time)
          bf16x8 b = sbuf[j * 64 + l];
          C[0][f % 5] = MFMA16(a1[0][f / 5], b, C[0][f % 5]);
          C[1][f % 5] = MFMA16(a1[1][f / 5], b, C[1][f % 5]);
        }
        __syncthreads();
        ++gc;
      }
      // bias + celu -> hbuf cols [80p, 80p+80)
#pragma unroll
      for (int nt = 0; nt < 5; ++nt) {
        float bias = ldbf(m * 512 + p * 80 + nt * 16 + l15);
#pragma unroll
        for (int mt = 0; mt < 2; ++mt)
#pragma unroll
          for (int r = 0; r < 4; ++r)
            hbuf[w][mt * 16 + l4 * 4 + r][p * 80 + nt * 16 + l15] =
                (__bf16)celu01(C[mt][nt][r] + bias);
      }
    }

    // ===== Layer 2: [32,160]x[160,128] in two N-halves of 64 (5 chunks ea) =====
    bf16x8 a2[2][5];
#pragma unroll
    for (int mt = 0; mt < 2; ++mt)
#pragma unroll
      for (int kf = 0; kf < 5; ++kf)
        a2[mt][kf] = *(const bf16x8*)&hbuf[w][mt * 16 + l15][kf * 32 + l4 * 8];

#pragma unroll 1
    for (int p = 0; p < 2; ++p) {
      f32x4 C[2][4];
#pragma unroll
      for (int mt = 0; mt < 2; ++mt)
#pragma unroll
        for (int nt = 0; nt < 4; ++nt) {
          f32x4 z; z[0] = z[1] = z[2] = z[3] = 0.f; C[mt][nt] = z;
        }
#pragma unroll
      for (int c = 0; c < 5; ++c) {
        stage_next(gc + 1);
        const bf16x8* sbuf = (const bf16x8*)((const char*)stage + ((gc & 1) << 12));
#pragma unroll
        for (int j = 0; j < 4; ++j) {
          const int f = c * 4 + j;    // kf = f/4, nth = f%4
          bf16x8 b = sbuf[j * 64 + l];
          C[0][f % 4] = MFMA16(a2[0][f / 4], b, C[0][f % 4]);
          C[1][f % 4] = MFMA16(a2[1][f / 4], b, C[1][f % 4]);
        }
        __syncthreads();
        ++gc;
      }
#pragma unroll
      for (int nt = 0; nt < 4; ++nt) {
        float bias = ldbf(m * 512 + 160 + p * 64 + nt * 16 + l15);
#pragma unroll
        for (int mt = 0; mt < 2; ++mt)
#pragma unroll
          for (int r = 0; r < 4; ++r)
            hbuf[w][mt * 16 + l4 * 4 + r][p * 64 + nt * 16 + l15] =
                (__bf16)celu01(C[mt][nt][r] + bias);
      }
    }

    // ===== Layer 3+4: [32,128]x[128,96] in two N-halves of 48 (3 chunks ea),
    // L4 dot-product folded into each pass epilogue =====
    bf16x8 a3[2][4];
#pragma unroll
    for (int mt = 0; mt < 2; ++mt)
#pragma unroll
      for (int kf = 0; kf < 4; ++kf)
        a3[mt][kf] = *(const bf16x8*)&hbuf[w][mt * 16 + l15][kf * 32 + l4 * 8];

    float e[2][4] = {{0.f, 0.f, 0.f, 0.f}, {0.f, 0.f, 0.f, 0.f}};
#pragma unroll 1
    for (int p = 0; p < 2; ++p) {
      f32x4 C[2][3];
#pragma unroll
      for (int mt = 0; mt < 2; ++mt)
#pragma unroll
        for (int nt = 0; nt < 3; ++nt) {
          f32x4 z; z[0] = z[1] = z[2] = z[3] = 0.f; C[mt][nt] = z;
        }
#pragma unroll
      for (int c = 0; c < 3; ++c) {
        stage_next(gc + 1);
        const bf16x8* sbuf = (const bf16x8*)((const char*)stage + ((gc & 1) << 12));
#pragma unroll
        for (int j = 0; j < 4; ++j) {
          const int f = c * 4 + j;    // kf = f/3, nth = f%3
          bf16x8 b = sbuf[j * 64 + l];
          C[0][f % 3] = MFMA16(a3[0][f / 3], b, C[0][f % 3]);
          C[1][f % 3] = MFMA16(a3[1][f / 3], b, C[1][f % 3]);
        }
        __syncthreads();
        ++gc;
      }
#pragma unroll
      for (int nt = 0; nt < 3; ++nt) {
        float b3v = ldbf(m * 512 + 288 + p * 48 + nt * 16 + l15);
        float w4v = ldbf(m * 512 + 384 + p * 48 + nt * 16 + l15);
#pragma unroll
        for (int mt = 0; mt < 2; ++mt)
#pragma unroll
          for (int r = 0; r < 4; ++r)
            e[mt][r] += celu01(C[mt][nt][r] + b3v) * w4v;
      }
    }
#pragma unroll
    for (int mt = 0; mt < 2; ++mt)
#pragma unroll
      for (int r = 0; r < 4; ++r) acc4[mt][r] += e[mt][r];
    bbacc += ((const float*)pPar)[(size_t)(s * NMODELS + mh * MPB + m) * 256 + 240];
  } // models

  // ---- final: 16-lane reduce, mask pads, partial model-mean, atomic ----
  float tot = 0.f;
#pragma unroll
  for (int mt = 0; mt < 2; ++mt)
#pragma unroll
    for (int r = 0; r < 4; ++r) {
      float v = acc4[mt][r];
      v += __shfl_xor(v, 1);
      v += __shfl_xor(v, 2);
      v += __shfl_xor(v, 4);
      v += __shfl_xor(v, 8);
      int slot = sb * ABLK + w * 32 + mt * 16 + l4 * 4 + r;
      if (l15 == 0 && slot < NPER) tot += v + bbacc;
    }
  tot *= (1.f / NMODELS);
#pragma unroll
  for (int off = 1; off < 64; off <<= 1) tot += __shfl_xor(tot, off);
  if (l == 0) atomicAdd(out, tot);
}

extern "C" void kernel_launch(void* const* d_in, const int* in_sizes, int n_in,
                              void* d_out, int out_size, void* d_ws, size_t ws_size,
                              hipStream_t stream) {
  (void)in_sizes; (void)n_in; (void)out_size; (void)ws_size;
  const int* species = (const int*)d_in[0];
  const float* aev = (const float*)d_in[1];
  const float* W1 = (const float*)d_in[2];
  const float* b1 = (const float*)d_in[3];
  const float* W2 = (const float*)d_in[4];
  const float* b2 = (const float*)d_in[5];
  const float* W3 = (const float*)d_in[6];
  const float* b3 = (const float*)d_in[7];
  const float* W4 = (const float*)d_in[8];
  const float* b4 = (const float*)d_in[9];
  float* out = (float*)d_out;
  char* ws = (char*)d_ws;

  unsigned short* pAll = (unsigned short*)ws;
  unsigned short* pPar = (unsigned short*)(ws + PBIAS_OFF);
  int* order = (int*)(ws + ORDER_OFF);
  int* bcnt = (int*)(ws + BCNT_OFF);
  int* bpfx = (int*)(ws + BPFX_OFF);
  int* base = (int*)(ws + BASE_OFF);

  hipMemsetAsync(d_out, 0, sizeof(float), stream);

  count_kernel<<<NRBLK, 256, 0, stream>>>(species, bcnt);
  scan_kernel<<<1, 256, 0, stream>>>(bcnt, bpfx, base);
  route_kernel<<<NRBLK, 256, 0, stream>>>(species, bpfx, base, order);

  // pass-ordered pack: L1 in two 80-col halves, L2 two 64-col, L3 two 48-col
  {
    int total = NSP * NMODELS * D0 * 80 / 2;  // 491520
    pack_kernel<<<(total + 255) / 256, 256, 0, stream>>>(W1, (unsigned*)pAll, D0, D1, 5, 0, 0, total);
    pack_kernel<<<(total + 255) / 256, 256, 0, stream>>>(W1, (unsigned*)pAll, D0, D1, 5, 80, 60, total);
  }
  {
    int total = NSP * NMODELS * D1 * 64 / 2;  // 163840
    pack_kernel<<<(total + 255) / 256, 256, 0, stream>>>(W2, (unsigned*)pAll, D1, D2, 4, 0, 120, total);
    pack_kernel<<<(total + 255) / 256, 256, 0, stream>>>(W2, (unsigned*)pAll, D1, D2, 4, 64, 140, total);
  }
  {
    int total = NSP * NMODELS * D2 * 48 / 2;  // 98304
    pack_kernel<<<(total + 255) / 256, 256, 0, stream>>>(W3, (unsigned*)pAll, D2, D3, 3, 0, 160, total);
    pack_kernel<<<(total + 255) / 256, 256, 0, stream>>>(W3, (unsigned*)pAll, D2, D3, 3, 48, 172, total);
  }
  {
    int total = NSP * NMODELS * 512;
    param_pack<<<(total + 255) / 256, 256, 0, stream>>>(b1, b2, b3, W4, b4, pPar);
  }

  mlp_kernel<<<NSP * BPS * MSPLIT, 256, 0, stream>>>(aev, order, pAll, pPar, out);
}